// Round 7
// baseline (575.080 us; speedup 1.0000x reference)
//
#include <hip/hip_runtime.h>
#include <hip/hip_bf16.h>

typedef unsigned short u16;
typedef short s16x8 __attribute__((ext_vector_type(8)));
typedef float f32x4 __attribute__((ext_vector_type(4)));

#define MFMA_BF16(a, b, c) __builtin_amdgcn_mfma_f32_16x16x32_bf16((a), (b), (c), 0, 0, 0)

static constexpr int D_IN   = 64;
static constexpr int H_DIM  = 512;
static constexpr int M_TILE = 32;   // rows per block (256 thr / 4 waves)
static constexpr int AST    = 520;  // LDS row stride (bf16): b128 A-reads conflict-free
static constexpr int XST    = 72;   // LDS row stride for x tile

__device__ __forceinline__ u16 f2bf(float f) {
  unsigned u = __builtin_bit_cast(unsigned, f);
  u += 0x7fffu + ((u >> 16) & 1u);   // RNE
  return (u16)(u >> 16);
}
__device__ __forceinline__ float bfb2f(unsigned bits16) {
  return __builtin_bit_cast(float, bits16 << 16);
}
__device__ __forceinline__ float fast_tanh(float x) {
  float e = __expf(2.0f * x);
  return 1.0f - 2.0f * __builtin_amdgcn_rcpf(e + 1.0f);
}

// ---- prep: fp32 weights -> bf16, packed in MFMA-B-fragment order ----
// (unchanged; layouts identical to rounds 0/6)
__global__ __launch_bounds__(256) void prep_weights(const float* __restrict__ W0,
                                                    const float* __restrict__ W1,
                                                    const float* __restrict__ W2,
                                                    u16* __restrict__ ws) {
  u16* p0f = ws;                       // fwd W0: K=64,  N=512
  u16* p0b = p0f + D_IN * H_DIM;       // bwd W0^T: K=512, N=64
  u16* p1f = p0b + D_IN * H_DIM;
  u16* p1b = p1f + H_DIM * H_DIM;
  u16* p2f = p1b + H_DIM * H_DIM;
  u16* p2b = p2f + H_DIM * H_DIM;

  __shared__ __align__(16) u16 tile[64 * 72];   // 9.0 KB

  int b = blockIdx.x;
  const float* src;
  u16 *dstf, *dstb;
  int rb, cb;
  bool isW0;
  if (b < 64) {
    src = W1; dstf = p1f; dstb = p1b; rb = b >> 3; cb = b & 7; isW0 = false;
  } else if (b < 128) {
    src = W2; dstf = p2f; dstb = p2b; rb = (b - 64) >> 3; cb = (b - 64) & 7; isW0 = false;
  } else {
    src = W0; dstf = p0f; dstb = p0b; rb = 0; cb = b - 128; isW0 = true;
  }

  const int tid = threadIdx.x;

  {
    int r = tid >> 2, cc = (tid & 3) * 16;
    const float4* s4 = (const float4*)(src + (size_t)(rb * 64 + r) * 512 + cb * 64 + cc);
    unsigned pk[8];
    #pragma unroll
    for (int v = 0; v < 4; ++v) {
      float4 f = s4[v];
      pk[v * 2]     = (unsigned)f2bf(f.x) | ((unsigned)f2bf(f.y) << 16);
      pk[v * 2 + 1] = (unsigned)f2bf(f.z) | ((unsigned)f2bf(f.w) << 16);
    }
    uint4* d = (uint4*)(tile + r * 72 + cc);
    d[0] = make_uint4(pk[0], pk[1], pk[2], pk[3]);
    d[1] = make_uint4(pk[4], pk[5], pk[6], pk[7]);
  }
  __syncthreads();

  const int c   = tid >> 6;
  const int kcl = (tid >> 5) & 1;
  const int ls  = (tid * 2) & 63;
  const int q   = ls >> 4;
  const int ln  = ls & 15;

  {
    __align__(16) u16 o[16];
    #pragma unroll
    for (int half = 0; half < 2; ++half)
      #pragma unroll
      for (int j = 0; j < 8; ++j)
        o[half * 8 + j] = tile[(kcl * 32 + q * 8 + j) * 72 + c * 16 + ln + half];
    int ntg   = 4 * cb + c;
    int kc    = 2 * rb + kcl;
    int chunk = isW0 ? (ntg * 2 + kc) : (ntg * 16 + kc);
    u16* dp = dstf + ((size_t)chunk * 64 + ls) * 8;
    *(uint4*)dp       = *(const uint4*)o;
    *(uint4*)(dp + 8) = *(const uint4*)(o + 8);
  }

  {
    const u16* rp = tile + (c * 16 + ln) * 72 + kcl * 32 + q * 8;
    s16x8 r0 = *(const s16x8*)rp;
    s16x8 r1 = *(const s16x8*)(rp + 72);
    int ntg = 4 * rb + c;
    int kc  = 2 * cb + kcl;
    u16* dp = dstb + ((size_t)(ntg * 16 + kc) * 64 + ls) * 8;
    *(s16x8*)dp       = r0;
    *(s16x8*)(dp + 8) = r1;
  }
}

// Load this wave's 8 B-tiles (ntg = 8*wave + s, s=0..7) of k-chunk KC into BR[8].
// W1/W2 packs: chunk=(ntg*16+kc) -> off = (wave<<16)+(s<<13)+(KC<<9) u16.
#define LOAD_B8(BP, KC, BR)                                                     \
  {                                                                             \
    const u16* _sr = (BP) + ((size_t)wave << 16) + ((KC) << 9) + lane * 8;      \
    _Pragma("unroll")                                                           \
    for (int s = 0; s < 8; ++s)                                                 \
      (BR)[s] = *(const s16x8*)(_sr + (s << 13));                               \
  }

// 512-wide GEMM K-loop: wave = 32 rows x 128 cols (2 m-tiles x 8 n-tiles).
// A from LDS buffer RB (2 b128 reads feed 16 MFMA -> A-read traffic halved
// vs the 64x64 slice); B all-register, 2-deep dbuf.
#define GEMM512_REG(BP, RB)                                                     \
  {                                                                             \
    _Pragma("unroll") for (int mt = 0; mt < 2; ++mt)                            \
      _Pragma("unroll") for (int nt = 0; nt < 8; ++nt)                          \
        acc[mt][nt] = (f32x4){0.f, 0.f, 0.f, 0.f};                              \
    for (int kc2 = 0; kc2 < 8; ++kc2) {                                         \
      const int e = kc2 * 2;                                                    \
      {                                                                         \
        s16x8 a[2];                                                             \
        _Pragma("unroll")                                                       \
        for (int mt = 0; mt < 2; ++mt)                                          \
          a[mt] = *(const s16x8*)((RB) + (mt * 16 + ln) * AST + e * 32 + q * 8);\
        _Pragma("unroll")                                                       \
        for (int nt = 0; nt < 8; ++nt)                                          \
          _Pragma("unroll")                                                     \
          for (int mt = 0; mt < 2; ++mt)                                        \
            acc[mt][nt] = MFMA_BF16(a[mt], bregA[nt], acc[mt][nt]);             \
        if (kc2 < 7) LOAD_B8(BP, e + 2, bregA);                                 \
      }                                                                         \
      const int o = e + 1;                                                      \
      {                                                                         \
        s16x8 a[2];                                                             \
        _Pragma("unroll")                                                       \
        for (int mt = 0; mt < 2; ++mt)                                          \
          a[mt] = *(const s16x8*)((RB) + (mt * 16 + ln) * AST + o * 32 + q * 8);\
        _Pragma("unroll")                                                       \
        for (int nt = 0; nt < 8; ++nt)                                          \
          _Pragma("unroll")                                                     \
          for (int mt = 0; mt < 2; ++mt)                                        \
            acc[mt][nt] = MFMA_BF16(a[mt], bregB[nt], acc[mt][nt]);             \
        if (kc2 < 7) LOAD_B8(BP, o + 2, bregB);                                 \
      }                                                                         \
    }                                                                           \
  }

// 256-thread block (4 waves), M_TILE=32, wave = 32x128 slice.
// LDS 71K/block -> TWO blocks co-resident per CU: independent blocks drift
// anti-phase, so one block's MFMA K-loop overlaps the other's VALU epilogue
// (the lockstep phase-alternation capped both pipes at ~40%).
// Ping-pong bufs (6 barriers, round-6 structure). VGPR ~238 < 256 @ 2 waves/EU.
__global__ __launch_bounds__(256, 2) void hnn_fused(
    const float* __restrict__ x,
    const float* __restrict__ bias0,
    const float* __restrict__ bias1,
    const float* __restrict__ bias2,
    const float* __restrict__ W3,
    const u16* __restrict__ ws,
    float* __restrict__ out)
{
  const u16* p0f = ws;
  const u16* p0b = p0f + D_IN * H_DIM;
  const u16* p1f = p0b + D_IN * H_DIM;
  const u16* p1b = p1f + H_DIM * H_DIM;
  const u16* p2f = p1b + H_DIM * H_DIM;
  const u16* p2b = p2f + H_DIM * H_DIM;

  __shared__ __align__(16) u16 xs[M_TILE * XST];     // 4.5 KB
  __shared__ __align__(16) u16 bufA[M_TILE * AST];   // 33.3 KB
  __shared__ __align__(16) u16 bufB[M_TILE * AST];   // 33.3 KB

  const int tid  = threadIdx.x;
  const int wave = tid >> 6;      // 0..3
  const int lane = tid & 63;
  const int ln   = lane & 15;
  const int q    = lane >> 4;
  const int nwb  = wave * 128;    // wave's 128-col slice
  const int row0 = blockIdx.x * M_TILE;

  // ---- stage x tile: 32x64 fp32 -> bf16 LDS (256 thr x 8 elems) ----
  {
    int r = tid >> 3, c = (tid & 7) * 8;
    const float4* src = (const float4*)(x + (size_t)(row0 + r) * D_IN + c);
    float4 f0 = src[0];
    float4 f1 = src[1];
    u16* dst = xs + r * XST + c;
    dst[0] = f2bf(f0.x); dst[1] = f2bf(f0.y); dst[2] = f2bf(f0.z); dst[3] = f2bf(f0.w);
    dst[4] = f2bf(f1.x); dst[5] = f2bf(f1.y); dst[6] = f2bf(f1.z); dst[7] = f2bf(f1.w);
  }
  __syncthreads();

  f32x4 acc[2][8];
  s16x8 bregA[8], bregB[8];   // register-B double buffer
  unsigned h0p[2][8][2];      // h0 bf16x2-packed, C-layout (for tanh' in bwd)
  unsigned h1p[2][8][2];
  float bias[8];

  // ================ GEMM0: z0 = x @ W0  (K=64, register-B) ================
  #pragma unroll
  for (int nt = 0; nt < 8; ++nt) bias[nt] = bias0[nwb + nt * 16 + ln];
  #pragma unroll
  for (int mt = 0; mt < 2; ++mt)
    #pragma unroll
    for (int nt = 0; nt < 8; ++nt) acc[mt][nt] = (f32x4){0.f, 0.f, 0.f, 0.f};
  {
    // p0f chunk = ntg*2+kc, ntg = 8*wave+nt -> off = (wave<<13)+(nt<<10)+(kc<<9)
    const u16* bpw0 = p0f + ((size_t)wave << 13) + lane * 8;
    #pragma unroll
    for (int kc = 0; kc < 2; ++kc) {
      s16x8 a[2];
      #pragma unroll
      for (int mt = 0; mt < 2; ++mt)
        a[mt] = *(const s16x8*)(xs + (mt * 16 + ln) * XST + kc * 32 + q * 8);
      #pragma unroll
      for (int nt = 0; nt < 8; ++nt) {
        s16x8 b = *(const s16x8*)(bpw0 + (nt << 10) + (kc << 9));
        #pragma unroll
        for (int mt = 0; mt < 2; ++mt)
          acc[mt][nt] = MFMA_BF16(a[mt], b, acc[mt][nt]);
      }
    }
  }
  LOAD_B8(p1f, 0, bregA);   // prefetch GEMM1 kc 0,1; overlaps epilogue VALU
  LOAD_B8(p1f, 1, bregB);
  // epi0: h0 = tanh(z0+b0) -> regs + bufA
  #pragma unroll
  for (int mt = 0; mt < 2; ++mt)
    #pragma unroll
    for (int nt = 0; nt < 8; ++nt) {
      int col = nwb + nt * 16 + ln;
      u16 u[4];
      #pragma unroll
      for (int r = 0; r < 4; ++r) {
        float th = fast_tanh(acc[mt][nt][r] + bias[nt]);
        u[r] = f2bf(th);
        bufA[(mt * 16 + q * 4 + r) * AST + col] = u[r];
      }
      h0p[mt][nt][0] = (unsigned)u[0] | ((unsigned)u[1] << 16);
      h0p[mt][nt][1] = (unsigned)u[2] | ((unsigned)u[3] << 16);
    }
  __syncthreads();

  // ================ GEMM1: z1 = h0 @ W1  (reads A, writes B) ================
  #pragma unroll
  for (int nt = 0; nt < 8; ++nt) bias[nt] = bias1[nwb + nt * 16 + ln];
  GEMM512_REG(p1f, bufA);
  LOAD_B8(p2f, 0, bregA);   // prefetch GEMM2
  LOAD_B8(p2f, 1, bregB);
  #pragma unroll
  for (int mt = 0; mt < 2; ++mt)
    #pragma unroll
    for (int nt = 0; nt < 8; ++nt) {
      int col = nwb + nt * 16 + ln;
      u16 u[4];
      #pragma unroll
      for (int r = 0; r < 4; ++r) {
        float th = fast_tanh(acc[mt][nt][r] + bias[nt]);
        u[r] = f2bf(th);
        bufB[(mt * 16 + q * 4 + r) * AST + col] = u[r];
      }
      h1p[mt][nt][0] = (unsigned)u[0] | ((unsigned)u[1] << 16);
      h1p[mt][nt][1] = (unsigned)u[2] | ((unsigned)u[3] << 16);
    }
  __syncthreads();

  // ================ GEMM2: z2 = h1 @ W2 ; gz2 = W3*(1-h2^2)  (reads B, writes A) ====
  #pragma unroll
  for (int nt = 0; nt < 8; ++nt) bias[nt] = bias2[nwb + nt * 16 + ln];
  float w3v[8];
  #pragma unroll
  for (int nt = 0; nt < 8; ++nt) w3v[nt] = W3[nwb + nt * 16 + ln];
  GEMM512_REG(p2f, bufB);
  LOAD_B8(p2b, 0, bregA);   // prefetch GEMM3
  LOAD_B8(p2b, 1, bregB);
  #pragma unroll
  for (int mt = 0; mt < 2; ++mt)
    #pragma unroll
    for (int nt = 0; nt < 8; ++nt) {
      int col = nwb + nt * 16 + ln;
      #pragma unroll
      for (int r = 0; r < 4; ++r) {
        float th = fast_tanh(acc[mt][nt][r] + bias[nt]);
        float gz = w3v[nt] * (1.0f - th * th);
        bufA[(mt * 16 + q * 4 + r) * AST + col] = f2bf(gz);
      }
    }
  __syncthreads();

  // ================ GEMM3: g1 = gz2 @ W2^T ; gz1 = g1*(1-h1^2)  (reads A, writes B) ==
  GEMM512_REG(p2b, bufA);
  LOAD_B8(p1b, 0, bregA);   // prefetch GEMM4
  LOAD_B8(p1b, 1, bregB);
  #pragma unroll
  for (int mt = 0; mt < 2; ++mt)
    #pragma unroll
    for (int nt = 0; nt < 8; ++nt) {
      int col = nwb + nt * 16 + ln;
      unsigned pa = h1p[mt][nt][0], pb = h1p[mt][nt][1];
      float hh[4] = { bfb2f(pa & 0xffffu), bfb2f(pa >> 16),
                      bfb2f(pb & 0xffffu), bfb2f(pb >> 16) };
      #pragma unroll
      for (int r = 0; r < 4; ++r) {
        float gz = acc[mt][nt][r] * (1.0f - hh[r] * hh[r]);
        bufB[(mt * 16 + q * 4 + r) * AST + col] = f2bf(gz);
      }
    }
  __syncthreads();

  // ================ GEMM4: g0 = gz1 @ W1^T ; gz0 = g0*(1-h0^2)  (reads B, writes A) ==
  GEMM512_REG(p1b, bufB);
  #pragma unroll
  for (int mt = 0; mt < 2; ++mt)
    #pragma unroll
    for (int nt = 0; nt < 8; ++nt) {
      int col = nwb + nt * 16 + ln;
      unsigned pa = h0p[mt][nt][0], pb = h0p[mt][nt][1];
      float hh[4] = { bfb2f(pa & 0xffffu), bfb2f(pa >> 16),
                      bfb2f(pb & 0xffffu), bfb2f(pb >> 16) };
      #pragma unroll
      for (int r = 0; r < 4; ++r) {
        float gz = acc[mt][nt][r] * (1.0f - hh[r] * hh[r]);
        bufA[(mt * 16 + q * 4 + r) * AST + col] = f2bf(gz);
      }
    }
  __syncthreads();

  // ================ GEMM5: gradH = gz0 @ W0^T (32x64), symplectic store ======
  // 4 waves x two 16x16 tiles: row tile mt5 = wave&1, col pair nt5 = 2*(wave>>1)+i.
  {
    f32x4 acc5[2];
    acc5[0] = (f32x4){0.f, 0.f, 0.f, 0.f};
    acc5[1] = (f32x4){0.f, 0.f, 0.f, 0.f};
    const int mt5 = wave & 1;                  // row tile 0..1
    const int np5 = (wave >> 1) * 2;           // col tile pair base (0 or 2)
    const u16* bp5 = p0b + ((size_t)np5 << 13) + lane * 8;  // chunk=(ntg*16+kc)*512
    #pragma unroll 2
    for (int kc = 0; kc < 16; ++kc) {
      s16x8 a = *(const s16x8*)(bufA + (mt5 * 16 + ln) * AST + kc * 32 + q * 8);
      #pragma unroll
      for (int i = 0; i < 2; ++i) {
        s16x8 b = *(const s16x8*)(bp5 + (i << 13) + (kc << 9));
        acc5[i] = MFMA_BF16(a, b, acc5[i]);
      }
    }
    #pragma unroll
    for (int i = 0; i < 2; ++i) {
      int g = (np5 + i) * 16 + ln;                // gradH column
      int c = (g < 32) ? g + 32 : g - 32;         // out = concat(gradH[:,32:], -gradH[:,:32])
      float s = (g < 32) ? -1.0f : 1.0f;
      #pragma unroll
      for (int r = 0; r < 4; ++r) {
        int grow = row0 + mt5 * 16 + q * 4 + r;
        out[(size_t)grow * 64 + c] = s * acc5[i][r];
      }
    }
  }
}

extern "C" void kernel_launch(void* const* d_in, const int* in_sizes, int n_in,
                              void* d_out, int out_size, void* d_ws, size_t ws_size,
                              hipStream_t stream) {
  // setup_inputs order: t, x, W0, b0, W1, b1, W2, b2, W3, b3
  const float* x  = (const float*)d_in[1];
  const float* W0 = (const float*)d_in[2];
  const float* b0 = (const float*)d_in[3];
  const float* W1 = (const float*)d_in[4];
  const float* b1 = (const float*)d_in[5];
  const float* W2 = (const float*)d_in[6];
  const float* b2 = (const float*)d_in[7];
  const float* W3 = (const float*)d_in[8];
  u16* ws = (u16*)d_ws;
  float* out = (float*)d_out;

  prep_weights<<<136, 256, 0, stream>>>(W0, W1, W2, ws);
  hnn_fused<<<65536 / M_TILE, 256, 0, stream>>>(x, b0, b1, b2, W3, ws, out);
}

// Round 8
// 332.555 us; speedup vs baseline: 1.7293x; 1.7293x over previous
//
#include <hip/hip_runtime.h>
#include <hip/hip_bf16.h>

typedef unsigned short u16;
typedef short s16x8 __attribute__((ext_vector_type(8)));
typedef float f32x4 __attribute__((ext_vector_type(4)));

#define MFMA_BF16(a, b, c) __builtin_amdgcn_mfma_f32_16x16x32_bf16((a), (b), (c), 0, 0, 0)

static constexpr int D_IN   = 64;
static constexpr int H_DIM  = 512;
static constexpr int M_TILE = 64;   // rows per block = two 32-row half-tiles
static constexpr int AST    = 520;  // LDS row stride (bf16): b128 A-reads conflict-free
static constexpr int XST    = 72;   // LDS row stride for x tile

__device__ __forceinline__ u16 f2bf(float f) {
  unsigned u = __builtin_bit_cast(unsigned, f);
  u += 0x7fffu + ((u >> 16) & 1u);   // RNE
  return (u16)(u >> 16);
}
__device__ __forceinline__ float bfb2f(unsigned bits16) {
  return __builtin_bit_cast(float, bits16 << 16);
}
__device__ __forceinline__ float fast_tanh(float x) {
  float e = __expf(2.0f * x);
  return 1.0f - 2.0f * __builtin_amdgcn_rcpf(e + 1.0f);
}

// ---- prep: fp32 weights -> bf16, packed in MFMA-B-fragment order ----
// (unchanged from rounds 0/6)
__global__ __launch_bounds__(256) void prep_weights(const float* __restrict__ W0,
                                                    const float* __restrict__ W1,
                                                    const float* __restrict__ W2,
                                                    u16* __restrict__ ws) {
  u16* p0f = ws;                       // fwd W0: K=64,  N=512
  u16* p0b = p0f + D_IN * H_DIM;       // bwd W0^T: K=512, N=64
  u16* p1f = p0b + D_IN * H_DIM;
  u16* p1b = p1f + H_DIM * H_DIM;
  u16* p2f = p1b + H_DIM * H_DIM;
  u16* p2b = p2f + H_DIM * H_DIM;

  __shared__ __align__(16) u16 tile[64 * 72];   // 9.0 KB

  int b = blockIdx.x;
  const float* src;
  u16 *dstf, *dstb;
  int rb, cb;
  bool isW0;
  if (b < 64) {
    src = W1; dstf = p1f; dstb = p1b; rb = b >> 3; cb = b & 7; isW0 = false;
  } else if (b < 128) {
    src = W2; dstf = p2f; dstb = p2b; rb = (b - 64) >> 3; cb = (b - 64) & 7; isW0 = false;
  } else {
    src = W0; dstf = p0f; dstb = p0b; rb = 0; cb = b - 128; isW0 = true;
  }

  const int tid = threadIdx.x;

  {
    int r = tid >> 2, cc = (tid & 3) * 16;
    const float4* s4 = (const float4*)(src + (size_t)(rb * 64 + r) * 512 + cb * 64 + cc);
    unsigned pk[8];
    #pragma unroll
    for (int v = 0; v < 4; ++v) {
      float4 f = s4[v];
      pk[v * 2]     = (unsigned)f2bf(f.x) | ((unsigned)f2bf(f.y) << 16);
      pk[v * 2 + 1] = (unsigned)f2bf(f.z) | ((unsigned)f2bf(f.w) << 16);
    }
    uint4* d = (uint4*)(tile + r * 72 + cc);
    d[0] = make_uint4(pk[0], pk[1], pk[2], pk[3]);
    d[1] = make_uint4(pk[4], pk[5], pk[6], pk[7]);
  }
  __syncthreads();

  const int c   = tid >> 6;
  const int kcl = (tid >> 5) & 1;
  const int ls  = (tid * 2) & 63;
  const int q   = ls >> 4;
  const int ln  = ls & 15;

  {
    __align__(16) u16 o[16];
    #pragma unroll
    for (int half = 0; half < 2; ++half)
      #pragma unroll
      for (int j = 0; j < 8; ++j)
        o[half * 8 + j] = tile[(kcl * 32 + q * 8 + j) * 72 + c * 16 + ln + half];
    int ntg   = 4 * cb + c;
    int kc    = 2 * rb + kcl;
    int chunk = isW0 ? (ntg * 2 + kc) : (ntg * 16 + kc);
    u16* dp = dstf + ((size_t)chunk * 64 + ls) * 8;
    *(uint4*)dp       = *(const uint4*)o;
    *(uint4*)(dp + 8) = *(const uint4*)(o + 8);
  }

  {
    const u16* rp = tile + (c * 16 + ln) * 72 + kcl * 32 + q * 8;
    s16x8 r0 = *(const s16x8*)rp;
    s16x8 r1 = *(const s16x8*)(rp + 72);
    int ntg = 4 * rb + c;
    int kc  = 2 * cb + kcl;
    u16* dp = dstb + ((size_t)(ntg * 16 + kc) * 64 + ls) * 8;
    *(s16x8*)dp       = r0;
    *(s16x8*)(dp + 8) = r1;
  }
}

// Load this wave's 4 B-tiles of k-chunk KC into BR[4] (1KB contiguous, L2-hot).
#define LOAD_B4(BP, KC, BR)                                                     \
  {                                                                             \
    const u16* _sr = (BP) + ((size_t)wave << 15) + ((KC) << 9) + lane * 8;      \
    _Pragma("unroll")                                                           \
    for (int s = 0; s < 4; ++s)                                                 \
      (BR)[s] = *(const s16x8*)(_sr + (s << 13));                               \
  }

#define ZACC(ACC)                                                               \
  _Pragma("unroll") for (int zm = 0; zm < 2; ++zm)                              \
    _Pragma("unroll") for (int zn = 0; zn < 4; ++zn)                            \
      ACC[zm][zn] = (f32x4){0.f, 0.f, 0.f, 0.f};

// ---- epilogue units (one (MT,NT) 4-row strip each; all indices compile-time) ----
// tanh + store + keep packed h (levels 0,1)
#define EPI_H(MT, NT, ACC, HP, BV, DB)                                          \
  {                                                                             \
    float t0_ = fast_tanh(ACC[MT][NT][0] + BV[NT]);                             \
    float t1_ = fast_tanh(ACC[MT][NT][1] + BV[NT]);                             \
    float t2_ = fast_tanh(ACC[MT][NT][2] + BV[NT]);                             \
    float t3_ = fast_tanh(ACC[MT][NT][3] + BV[NT]);                             \
    u16 u0_ = f2bf(t0_), u1_ = f2bf(t1_), u2_ = f2bf(t2_), u3_ = f2bf(t3_);     \
    u16* bp_ = (DB) + ((MT) * 16 + q * 4) * AST + nwb + (NT) * 16 + ln;         \
    bp_[0] = u0_; bp_[AST] = u1_; bp_[2 * AST] = u2_; bp_[3 * AST] = u3_;       \
    HP[MT][NT][0] = (unsigned)u0_ | ((unsigned)u1_ << 16);                      \
    HP[MT][NT][1] = (unsigned)u2_ | ((unsigned)u3_ << 16);                      \
  }
// gz2 = W3 * (1 - tanh(z2+b2)^2)  (level 2)
#define EPI_G2(MT, NT, ACC, DB)                                                 \
  {                                                                             \
    u16* bp_ = (DB) + ((MT) * 16 + q * 4) * AST + nwb + (NT) * 16 + ln;         \
    float t0_ = fast_tanh(ACC[MT][NT][0] + b2v[NT]);                            \
    float t1_ = fast_tanh(ACC[MT][NT][1] + b2v[NT]);                            \
    float t2_ = fast_tanh(ACC[MT][NT][2] + b2v[NT]);                            \
    float t3_ = fast_tanh(ACC[MT][NT][3] + b2v[NT]);                            \
    bp_[0]       = f2bf(w3v[NT] * (1.0f - t0_ * t0_));                          \
    bp_[AST]     = f2bf(w3v[NT] * (1.0f - t1_ * t1_));                          \
    bp_[2 * AST] = f2bf(w3v[NT] * (1.0f - t2_ * t2_));                          \
    bp_[3 * AST] = f2bf(w3v[NT] * (1.0f - t3_ * t3_));                          \
  }
// gz = g * (1 - h^2) from packed h (levels 3,4)
#define EPI_B(MT, NT, ACC, HP, DB)                                              \
  {                                                                             \
    unsigned pa_ = HP[MT][NT][0], pb_ = HP[MT][NT][1];                          \
    float h0_ = bfb2f(pa_ & 0xffffu), h1_ = bfb2f(pa_ >> 16);                   \
    float h2_ = bfb2f(pb_ & 0xffffu), h3_ = bfb2f(pb_ >> 16);                   \
    u16* bp_ = (DB) + ((MT) * 16 + q * 4) * AST + nwb + (NT) * 16 + ln;         \
    bp_[0]       = f2bf(ACC[MT][NT][0] * (1.0f - h0_ * h0_));                   \
    bp_[AST]     = f2bf(ACC[MT][NT][1] * (1.0f - h1_ * h1_));                   \
    bp_[2 * AST] = f2bf(ACC[MT][NT][2] * (1.0f - h2_ * h2_));                   \
    bp_[3 * AST] = f2bf(ACC[MT][NT][3] * (1.0f - h3_ * h3_));                   \
  }
#define EPI_NONE(MT, NT) {}

// One K-step (2 k-chunks = 16 MFMA) of the 32-row half-tile GEMM with one
// epilogue unit of the OTHER half-tile interleaved mid-step. K2 is a literal.
#define KSTEP(RB, ACC, BP, K2, EPIU)                                            \
  {                                                                             \
    s16x8 a0_ = *(const s16x8*)((RB) + (ln) * AST + (K2) * 64 + q * 8);         \
    s16x8 a1_ = *(const s16x8*)((RB) + (16 + ln) * AST + (K2) * 64 + q * 8);    \
    ACC[0][0] = MFMA_BF16(a0_, bregA[0], ACC[0][0]);                            \
    ACC[1][0] = MFMA_BF16(a1_, bregA[0], ACC[1][0]);                            \
    ACC[0][1] = MFMA_BF16(a0_, bregA[1], ACC[0][1]);                            \
    ACC[1][1] = MFMA_BF16(a1_, bregA[1], ACC[1][1]);                            \
    ACC[0][2] = MFMA_BF16(a0_, bregA[2], ACC[0][2]);                            \
    ACC[1][2] = MFMA_BF16(a1_, bregA[2], ACC[1][2]);                            \
    ACC[0][3] = MFMA_BF16(a0_, bregA[3], ACC[0][3]);                            \
    ACC[1][3] = MFMA_BF16(a1_, bregA[3], ACC[1][3]);                            \
    if ((K2) < 7) LOAD_B4(BP, (K2) * 2 + 2, bregA);                             \
    EPIU((K2) >> 2, (K2) & 3);                                                  \
    s16x8 a2_ = *(const s16x8*)((RB) + (ln) * AST + (K2) * 64 + 32 + q * 8);    \
    s16x8 a3_ = *(const s16x8*)((RB) + (16 + ln) * AST + (K2) * 64 + 32 + q * 8); \
    ACC[0][0] = MFMA_BF16(a2_, bregB[0], ACC[0][0]);                            \
    ACC[1][0] = MFMA_BF16(a3_, bregB[0], ACC[1][0]);                            \
    ACC[0][1] = MFMA_BF16(a2_, bregB[1], ACC[0][1]);                            \
    ACC[1][1] = MFMA_BF16(a3_, bregB[1], ACC[1][1]);                            \
    ACC[0][2] = MFMA_BF16(a2_, bregB[2], ACC[0][2]);                            \
    ACC[1][2] = MFMA_BF16(a3_, bregB[2], ACC[1][2]);                            \
    ACC[0][3] = MFMA_BF16(a2_, bregB[3], ACC[0][3]);                            \
    ACC[1][3] = MFMA_BF16(a3_, bregB[3], ACC[1][3]);                            \
    if ((K2) < 7) LOAD_B4(BP, (K2) * 2 + 3, bregB);                             \
  }

// Full 512-wide GEMM for a 32-row half-tile (wave = 32x64 slice, acc[2][4]),
// with the other half-tile's 8 epilogue units woven in (one per K-step).
#define GEMMF(RB, ACC, BP, EPIU)                                                \
  {                                                                             \
    ZACC(ACC);                                                                  \
    KSTEP(RB, ACC, BP, 0, EPIU); KSTEP(RB, ACC, BP, 1, EPIU);                   \
    KSTEP(RB, ACC, BP, 2, EPIU); KSTEP(RB, ACC, BP, 3, EPIU);                   \
    KSTEP(RB, ACC, BP, 4, EPIU); KSTEP(RB, ACC, BP, 5, EPIU);                   \
    KSTEP(RB, ACC, BP, 6, EPIU); KSTEP(RB, ACC, BP, 7, EPIU);                   \
  }

// 512 threads / 8 waves. Block = 64 rows as two 32-row half-tiles T0/T1,
// phase-skewed: each barrier segment = GEMM_k(Tcur) // epilogue_{k-1}(Tother).
// MFMA (GEMM) and VALU (epilogue) are dependency-free within a segment ->
// pipes overlap instead of time-sharing (round-6: 43% MFMA + 41% VALU serial).
// LDS: xs 9K + 4 x 32-row ping-pong bufs 133K = 142.3K (1 block/CU).
__global__ __launch_bounds__(512, 2) void hnn_fused(
    const float* __restrict__ x,
    const float* __restrict__ bias0,
    const float* __restrict__ bias1,
    const float* __restrict__ bias2,
    const float* __restrict__ W3,
    const u16* __restrict__ ws,
    float* __restrict__ out)
{
  const u16* p0f = ws;
  const u16* p0b = p0f + D_IN * H_DIM;
  const u16* p1f = p0b + D_IN * H_DIM;
  const u16* p1b = p1f + H_DIM * H_DIM;
  const u16* p2f = p1b + H_DIM * H_DIM;
  const u16* p2b = p2f + H_DIM * H_DIM;

  __shared__ __align__(16) u16 xs[M_TILE * XST];      // 9.0 KB (rows 0-31=T0, 32-63=T1)
  __shared__ __align__(16) u16 bufA0[32 * AST];       // 33.3 KB  T0 ping
  __shared__ __align__(16) u16 bufB0[32 * AST];       // 33.3 KB  T0 pong
  __shared__ __align__(16) u16 bufA1[32 * AST];       // 33.3 KB  T1 ping
  __shared__ __align__(16) u16 bufB1[32 * AST];       // 33.3 KB  T1 pong

  const int tid  = threadIdx.x;
  const int wave = tid >> 6;      // 0..7
  const int lane = tid & 63;
  const int ln   = lane & 15;
  const int q    = lane >> 4;
  const int nwb  = wave * 64;     // wave's 64-col (feature) slice
  const int row0 = blockIdx.x * M_TILE;

  // ---- stage x tile: 64x64 fp32 -> bf16 LDS ----
  {
    int r = tid >> 3, c = (tid & 7) * 8;
    const float4* src = (const float4*)(x + (size_t)(row0 + r) * D_IN + c);
    float4 f0 = src[0];
    float4 f1 = src[1];
    u16* dst = xs + r * XST + c;
    dst[0] = f2bf(f0.x); dst[1] = f2bf(f0.y); dst[2] = f2bf(f0.z); dst[3] = f2bf(f0.w);
    dst[4] = f2bf(f1.x); dst[5] = f2bf(f1.y); dst[6] = f2bf(f1.z); dst[7] = f2bf(f1.w);
  }

  // bias / W3 vectors for this wave's 64 features (held in regs all kernel)
  float b0v[4], b1v[4], b2v[4], w3v[4];
  #pragma unroll
  for (int nt = 0; nt < 4; ++nt) {
    b0v[nt] = bias0[nwb + nt * 16 + ln];
    b1v[nt] = bias1[nwb + nt * 16 + ln];
    b2v[nt] = bias2[nwb + nt * 16 + ln];
    w3v[nt] = W3[nwb + nt * 16 + ln];
  }
  __syncthreads();

  f32x4 accA[2][4], accB[2][4];          // T0 / T1 accumulators
  s16x8 bregA[4], bregB[4];              // register-B double buffer (shared)
  unsigned h0pA[2][4][2], h0pB[2][4][2]; // packed h0 per tile
  unsigned h1pA[2][4][2], h1pB[2][4][2]; // packed h1 per tile

  // ---- S0: G0(T0): z0_T0 = x[0:32] @ W0 (K=64) ----
  ZACC(accA);
  {
    const u16* bpw0 = p0f + (wave << 12) + lane * 8;
    #pragma unroll
    for (int kc = 0; kc < 2; ++kc) {
      s16x8 a0 = *(const s16x8*)(xs + (ln) * XST + kc * 32 + q * 8);
      s16x8 a1 = *(const s16x8*)(xs + (16 + ln) * XST + kc * 32 + q * 8);
      #pragma unroll
      for (int nt = 0; nt < 4; ++nt) {
        s16x8 b = *(const s16x8*)(bpw0 + (nt << 10) + (kc << 9));
        accA[0][nt] = MFMA_BF16(a0, b, accA[0][nt]);
        accA[1][nt] = MFMA_BF16(a1, b, accA[1][nt]);
      }
    }
  }
  LOAD_B4(p1f, 0, bregA);   // prefetch for S2
  LOAD_B4(p1f, 1, bregB);

  // ---- S1: G0(T1) + epi0(T0) -> bufA0, h0pA ----
  ZACC(accB);
  {
    const u16* bpw0 = p0f + (wave << 12) + lane * 8;
    #pragma unroll
    for (int kc = 0; kc < 2; ++kc) {
      s16x8 a0 = *(const s16x8*)(xs + (32 + ln) * XST + kc * 32 + q * 8);
      s16x8 a1 = *(const s16x8*)(xs + (48 + ln) * XST + kc * 32 + q * 8);
      #pragma unroll
      for (int nt = 0; nt < 4; ++nt) {
        s16x8 b = *(const s16x8*)(bpw0 + (nt << 10) + (kc << 9));
        accB[0][nt] = MFMA_BF16(a0, b, accB[0][nt]);
        accB[1][nt] = MFMA_BF16(a1, b, accB[1][nt]);
      }
    }
  }
  EPI_H(0, 0, accA, h0pA, b0v, bufA0); EPI_H(0, 1, accA, h0pA, b0v, bufA0);
  EPI_H(0, 2, accA, h0pA, b0v, bufA0); EPI_H(0, 3, accA, h0pA, b0v, bufA0);
  EPI_H(1, 0, accA, h0pA, b0v, bufA0); EPI_H(1, 1, accA, h0pA, b0v, bufA0);
  EPI_H(1, 2, accA, h0pA, b0v, bufA0); EPI_H(1, 3, accA, h0pA, b0v, bufA0);
  __syncthreads();

  // ---- S2: G1(T0) reads bufA0 // epi0(T1) -> bufA1, h0pB ----
  #define EPI0T1(MT, NT) EPI_H(MT, NT, accB, h0pB, b0v, bufA1)
  GEMMF(bufA0, accA, p1f, EPI0T1);
  LOAD_B4(p1f, 0, bregA);
  LOAD_B4(p1f, 1, bregB);
  __syncthreads();

  // ---- S3: G1(T1) reads bufA1 // epi1(T0) -> bufB0, h1pA ----
  #define EPI1T0(MT, NT) EPI_H(MT, NT, accA, h1pA, b1v, bufB0)
  GEMMF(bufA1, accB, p1f, EPI1T0);
  LOAD_B4(p2f, 0, bregA);
  LOAD_B4(p2f, 1, bregB);
  __syncthreads();

  // ---- S4: G2(T0) reads bufB0 // epi1(T1) -> bufB1, h1pB ----
  #define EPI1T1(MT, NT) EPI_H(MT, NT, accB, h1pB, b1v, bufB1)
  GEMMF(bufB0, accA, p2f, EPI1T1);
  LOAD_B4(p2f, 0, bregA);
  LOAD_B4(p2f, 1, bregB);
  __syncthreads();

  // ---- S5: G2(T1) reads bufB1 // epi2(T0) -> bufA0 ----
  #define EPI2T0(MT, NT) EPI_G2(MT, NT, accA, bufA0)
  GEMMF(bufB1, accB, p2f, EPI2T0);
  LOAD_B4(p2b, 0, bregA);
  LOAD_B4(p2b, 1, bregB);
  __syncthreads();

  // ---- S6: G3(T0) reads bufA0 // epi2(T1) -> bufA1 ----
  #define EPI2T1(MT, NT) EPI_G2(MT, NT, accB, bufA1)
  GEMMF(bufA0, accA, p2b, EPI2T1);
  LOAD_B4(p2b, 0, bregA);
  LOAD_B4(p2b, 1, bregB);
  __syncthreads();

  // ---- S7: G3(T1) reads bufA1 // epi3(T0) -> bufB0 ----
  #define EPI3T0(MT, NT) EPI_B(MT, NT, accA, h1pA, bufB0)
  GEMMF(bufA1, accB, p2b, EPI3T0);
  LOAD_B4(p1b, 0, bregA);
  LOAD_B4(p1b, 1, bregB);
  __syncthreads();

  // ---- S8: G4(T0) reads bufB0 // epi3(T1) -> bufB1 ----
  #define EPI3T1(MT, NT) EPI_B(MT, NT, accB, h1pB, bufB1)
  GEMMF(bufB0, accA, p1b, EPI3T1);
  LOAD_B4(p1b, 0, bregA);
  LOAD_B4(p1b, 1, bregB);
  __syncthreads();

  // ---- S9: G4(T1) reads bufB1 // epi4(T0) -> bufA0 ----
  #define EPI4T0(MT, NT) EPI_B(MT, NT, accA, h0pA, bufA0)
  GEMMF(bufB1, accB, p1b, EPI4T0);
  __syncthreads();

  // ---- S10: G5(T0) reads bufA0 // epi4(T1) -> bufA1 ----
  // 8 waves x one 16x16 tile: rows mt5 = wave&1, cols c5 = wave>>1 (0..3).
  const int mt5 = wave & 1;
  const int c5  = wave >> 1;
  const u16* bp5 = p0b + ((size_t)c5 << 13) + lane * 8;  // chunk=(c5*16+kc)*512
  {
    f32x4 acc5 = (f32x4){0.f, 0.f, 0.f, 0.f};
    #pragma unroll
    for (int kc = 0; kc < 16; ++kc) {
      s16x8 a = *(const s16x8*)(bufA0 + (mt5 * 16 + ln) * AST + kc * 32 + q * 8);
      s16x8 b = *(const s16x8*)(bp5 + (kc << 9));
      acc5 = MFMA_BF16(a, b, acc5);
    }
    EPI_B(0, 0, accB, h0pB, bufA1); EPI_B(0, 1, accB, h0pB, bufA1);
    EPI_B(0, 2, accB, h0pB, bufA1); EPI_B(0, 3, accB, h0pB, bufA1);
    EPI_B(1, 0, accB, h0pB, bufA1); EPI_B(1, 1, accB, h0pB, bufA1);
    EPI_B(1, 2, accB, h0pB, bufA1); EPI_B(1, 3, accB, h0pB, bufA1);
    int g = c5 * 16 + ln;
    int cc = (g < 32) ? g + 32 : g - 32;   // out = concat(gradH[:,32:], -gradH[:,:32])
    float sg = (g < 32) ? -1.0f : 1.0f;
    #pragma unroll
    for (int r = 0; r < 4; ++r) {
      int grow = row0 + mt5 * 16 + q * 4 + r;
      out[(size_t)grow * 64 + cc] = sg * acc5[r];
    }
  }
  __syncthreads();

  // ---- S11: G5(T1) reads bufA1 ----
  {
    f32x4 acc5 = (f32x4){0.f, 0.f, 0.f, 0.f};
    #pragma unroll
    for (int kc = 0; kc < 16; ++kc) {
      s16x8 a = *(const s16x8*)(bufA1 + (mt5 * 16 + ln) * AST + kc * 32 + q * 8);
      s16x8 b = *(const s16x8*)(bp5 + (kc << 9));
      acc5 = MFMA_BF16(a, b, acc5);
    }
    int g = c5 * 16 + ln;
    int cc = (g < 32) ? g + 32 : g - 32;
    float sg = (g < 32) ? -1.0f : 1.0f;
    #pragma unroll
    for (int r = 0; r < 4; ++r) {
      int grow = row0 + 32 + mt5 * 16 + q * 4 + r;
      out[(size_t)grow * 64 + cc] = sg * acc5[r];
    }
  }
}

extern "C" void kernel_launch(void* const* d_in, const int* in_sizes, int n_in,
                              void* d_out, int out_size, void* d_ws, size_t ws_size,
                              hipStream_t stream) {
  // setup_inputs order: t, x, W0, b0, W1, b1, W2, b2, W3, b3
  const float* x  = (const float*)d_in[1];
  const float* W0 = (const float*)d_in[2];
  const float* b0 = (const float*)d_in[3];
  const float* W1 = (const float*)d_in[4];
  const float* b1 = (const float*)d_in[5];
  const float* W2 = (const float*)d_in[6];
  const float* b2 = (const float*)d_in[7];
  const float* W3 = (const float*)d_in[8];
  u16* ws = (u16*)d_ws;
  float* out = (float*)d_out;

  prep_weights<<<136, 256, 0, stream>>>(W0, W1, W2, ws);
  hnn_fused<<<65536 / M_TILE, 512, 0, stream>>>(x, b0, b1, b2, W3, ws, out);
}